// Round 3
// baseline (262.940 us; speedup 1.0000x reference)
//
#include <hip/hip_runtime.h>
#include <hip/hip_bf16.h>
#include <math.h>

#define B_ 8
#define N_ 4096
#define C_ 256
#define DQK_ 32

typedef float f32x4  __attribute__((ext_vector_type(4)));
typedef float f32x16 __attribute__((ext_vector_type(16)));
typedef short bf16x8 __attribute__((ext_vector_type(8)));
typedef short bf16x4 __attribute__((ext_vector_type(4)));

__device__ __forceinline__ short f2bf(float f){
  union { float f; unsigned u; } v; v.f = f;
  unsigned r = v.u + 0x7fffu + ((v.u >> 16) & 1u);
  return (short)(r >> 16);
}

// ---------- kernel 1: weight transpose + cast -> WT[320][256] bf16 ----------
__global__ void cast_wt_kernel(const float* __restrict__ Wq, const float* __restrict__ Wk,
                               const float* __restrict__ Wv, short* __restrict__ WT){
  int n = blockIdx.x;        // 0..319 output channel
  int k = threadIdx.x;       // 0..255 input channel
  float val;
  if (n < 32)       val = Wq[k*32 + n];
  else if (n < 64)  val = Wk[k*32 + (n-32)];
  else              val = Wv[k*256 + (n-64)];
  WT[n*256 + k] = f2bf(val);
}

// ---------- kernel 2: projections -> frag-swizzled q,k,v ----------
__global__ __launch_bounds__(256) void proj_kernel(
    const float* __restrict__ x, const short* __restrict__ WT,
    const float* __restrict__ bq, const float* __restrict__ bk, const float* __restrict__ bv,
    short* __restrict__ qws, short* __restrict__ kws, short* __restrict__ vSw){
  __shared__ __align__(16) short sX[64*264];   // 67584 B
  __shared__ __align__(16) short sT[64*72];    // 9216 B  (q cols 0..31 | k cols 32..63)
  int tid = threadIdx.x;
  int lane = tid & 63, wave = tid >> 6;
  int lane15 = lane & 15, quad = lane >> 4;
  int mbase = blockIdx.x * 64;
  int b = mbase >> 12, kvb = mbase & (N_-1);

  const float* xr = x + (size_t)mbase * C_;
  for (int i = 0; i < 8; i++){
    int s = tid + i*256;
    int row = s >> 5, cg = (s & 31) << 3;
    const f32x4* src = (const f32x4*)(xr + row*C_ + cg);
    f32x4 a = src[0], c = src[1];
    bf16x8 p;
    p[0]=f2bf(a[0]); p[1]=f2bf(a[1]); p[2]=f2bf(a[2]); p[3]=f2bf(a[3]);
    p[4]=f2bf(c[0]); p[5]=f2bf(c[1]); p[6]=f2bf(c[2]); p[7]=f2bf(c[3]);
    *(bf16x8*)(sX + row*264 + cg) = p;
  }
  __syncthreads();

  f32x4 acc[5][4];
  for (int i=0;i<5;i++) for (int mt=0;mt<4;mt++) acc[i][mt] = (f32x4)(0.f);

  for (int kc = 0; kc < 8; kc++){
    bf16x8 afr[4];
    #pragma unroll
    for (int mt=0;mt<4;mt++)
      afr[mt] = *(const bf16x8*)(sX + (mt*16+lane15)*264 + kc*32 + quad*8);
    bf16x8 bfr[5];
    #pragma unroll
    for (int i=0;i<5;i++){
      int t = i*4 + wave;
      bfr[i] = *(const bf16x8*)(WT + (size_t)(t*16+lane15)*256 + kc*32 + quad*8);
    }
    #pragma unroll
    for (int i=0;i<5;i++)
      #pragma unroll
      for (int mt=0;mt<4;mt++)
        acc[i][mt] = __builtin_amdgcn_mfma_f32_16x16x32_bf16(afr[mt], bfr[i], acc[i][mt], 0,0,0);
  }

  #pragma unroll
  for (int i=0;i<5;i++){
    int t = i*4 + wave;
    int n0 = t*16 + lane15;
    float bias = (n0 < 32) ? bq[n0] : (n0 < 64 ? bk[n0-32] : bv[n0-64]);
    if (n0 < 64){
      #pragma unroll
      for (int mt=0;mt<4;mt++)
        #pragma unroll
        for (int r=0;r<4;r++)
          sT[(mt*16 + quad*4 + r)*72 + n0] = f2bf(acc[i][mt][r] + bias);
    } else {
      int ch = n0 - 64, cht = ch >> 5, c5 = ch & 31;
      int lanep = c5 | ((quad & 1) << 5);
      int jo = (quad >> 1) * 4;
      #pragma unroll
      for (int mt=0;mt<4;mt++){
        bf16x4 pk;
        pk[0]=f2bf(acc[i][mt][0]+bias); pk[1]=f2bf(acc[i][mt][1]+bias);
        pk[2]=f2bf(acc[i][mt][2]+bias); pk[3]=f2bf(acc[i][mt][3]+bias);
        size_t off = (size_t)b*1048576 + (size_t)(kvb>>6)*16384
                   + (size_t)(mt*8 + cht)*512 + (size_t)lanep*8 + jo;
        *(bf16x4*)(vSw + off) = pk;
      }
    }
  }
  __syncthreads();

  {
    int qt = tid >> 7, p = (tid >> 6) & 1, ln = tid & 63;
    int row = qt*32 + (ln & 31);
    int dcol = p*16 + (ln >> 5)*8;
    bf16x8 vq = *(const bf16x8*)(sT + row*72 + dcol);
    bf16x8 vk = *(const bf16x8*)(sT + row*72 + 32 + dcol);
    size_t qoff = ((((size_t)b*128 + ((kvb>>5) + qt))*2 + p)*64 + ln)*8;
    *(bf16x8*)(qws + qoff) = vq;
    size_t koff = ((size_t)b*64 + (kvb>>6))*2048 + (size_t)((qt*2 + p)*64 + ln)*8;
    *(bf16x8*)(kws + koff) = vk;
  }
}

// ---------- kernel 3: flash attention + residual (v4: 2 q-tiles/wave) ----------
// Diagnosis from v1/v2/v3: LDS-read-BW-bound. v1 read 128 KB of V frags per chunk/CU
// (4 waves share each kh half -> 4x amplification); v3 doubled staging and slowed by
// exactly the traffic ratio. Fix: register-level V reuse.
//   grid 256 x 256 thr, 1 block/CU, 4 waves (1/SIMD). wave = (qtp, kh):
//   2 q-tiles (qtp*2, qtp*2+1) x 256 ch x kv-half. Each V fragment read feeds 2 MFMAs
//   (accA, accB) -> V reads 64 KB/chunk/CU (was 128). acc = 256 AGPRs, ~390 regs total,
//   1 wave/SIMD (OccupancyPercent ~12% is intentional).
// At 1 wave/SIMD there is no partner wave to hide exp, so QK(t+1)+exp(t+1) is computed
// during interval t (K reg-prefetched 2 ahead in kE/kO ping-pong; all indices static):
// exp VALU is independent of PV(t) MFMAs and co-issues into the matrix-pipe gaps.
// Rowsum via VALU adds on exp values (frees 32 AGPRs + 16 MFMA/chunk/CU vs ones-MFMA).
__global__ __launch_bounds__(256, 1) void flash_kernel(
    const float* __restrict__ x, const short* __restrict__ qws, const short* __restrict__ kws,
    const short* __restrict__ vSw, const float* __restrict__ gptr, float* __restrict__ out){
  __shared__ __align__(16) char smem[67072];   // sV[2]=64KB; epi: R 64KB | RS 1KB | RSM 0.5KB
  short* sV0 = (short*)smem;
  short* sV1 = (short*)(smem + 32768);
  int tid = threadIdx.x;
  int lane = tid & 63, wave = tid >> 6;        // wave 0..3
  int l31 = lane & 31, h = lane >> 5;
  int qtp = wave >> 1, kh = wave & 1;
  int b = blockIdx.x & 7;
  int q0 = (blockIdx.x >> 3) << 7;             // 128 q-rows per block

  const short* qb = qws + (size_t)b*131072;
  const short* kb = kws + (size_t)b*131072;
  const short* vb = vSw + (size_t)b*1048576;

  int qtgA = (q0 >> 5) + qtp*2;                // global q-tile ids qtgA, qtgA+1
  bf16x8 qfA0 = *(const bf16x8*)(qb + (size_t)((qtgA*2+0)*64 + lane)*8);
  bf16x8 qfA1 = *(const bf16x8*)(qb + (size_t)((qtgA*2+1)*64 + lane)*8);
  bf16x8 qfB0 = *(const bf16x8*)(qb + (size_t)(((qtgA+1)*2+0)*64 + lane)*8);
  bf16x8 qfB1 = *(const bf16x8*)(qb + (size_t)(((qtgA+1)*2+1)*64 + lane)*8);

  const short* kf0p = kb + (size_t)((2*kh+0)*64 + lane)*8;
  const short* kf1p = kb + (size_t)((2*kh+1)*64 + lane)*8;
  // K ping-pong: kE = even chunks, kO = odd chunks (prefetched 2 chunks ahead)
  bf16x8 kE0 = *(const bf16x8*)(kf0p);             // K(0)
  bf16x8 kE1 = *(const bf16x8*)(kf1p);
  bf16x8 kO0 = *(const bf16x8*)(kf0p + 2048);      // K(1)
  bf16x8 kO1 = *(const bf16x8*)(kf1p + 2048);

#define VPREF(CHUNK, DST) do { \
    const short* vsrc_ = vb + (size_t)(CHUNK)*16384; \
    _Pragma("unroll") \
    for (int r_=0;r_<8;r_++) \
      __builtin_amdgcn_global_load_lds( \
        (const __attribute__((address_space(1))) void*)(vsrc_ + (size_t)(r_*256+tid)*8), \
        (__attribute__((address_space(3))) void*)((DST) + (size_t)(r_*256+tid)*8), 16, 0, 0); \
  } while(0)

#define EXPPACK(S, PF, RS) do { \
    float ls_ = 0.f; \
    _Pragma("unroll") \
    for (int g_=0; g_<2; g_++){ \
      union { bf16x8 v; unsigned u[4]; } P_; \
      _Pragma("unroll") \
      for (int j_=0;j_<4;j_++){ \
        float2 e_; \
        e_.x = __expf((S)[g_*8 + 2*j_]); \
        e_.y = __expf((S)[g_*8 + 2*j_ + 1]); \
        ls_ += e_.x + e_.y; \
        __hip_bfloat162 t2_ = __float22bfloat162_rn(e_); \
        __builtin_memcpy(&P_.u[j_], &t2_, 4); \
      } \
      (PF)[g_] = P_.v; \
    } \
    (RS) += ls_; \
  } while(0)

// QK + exp for both q-tiles of this wave, from the given K reg pair -> NFA/NFB
#define QK2(K0, K1, NFA, NFB) do { \
    f32x16 sA_ = __builtin_amdgcn_mfma_f32_32x32x16_bf16((K0), qfA0, (f32x16)(0.f), 0,0,0); \
    sA_        = __builtin_amdgcn_mfma_f32_32x32x16_bf16((K1), qfA1, sA_, 0,0,0); \
    f32x16 sB_ = __builtin_amdgcn_mfma_f32_32x32x16_bf16((K0), qfB0, (f32x16)(0.f), 0,0,0); \
    sB_        = __builtin_amdgcn_mfma_f32_32x32x16_bf16((K1), qfB1, sB_, 0,0,0); \
    EXPPACK(sA_, NFA, rsA); \
    EXPPACK(sB_, NFB, rsB); \
  } while(0)

// PV for current pf pair; each V fragment read feeds BOTH q-tiles (2x reuse)
#define PV2(SVC) do { \
    _Pragma("unroll") \
    for (int ks_=0; ks_<2; ks_++){ \
      const short* base_ = (SVC) + (2*kh + ks_)*4096; \
      _Pragma("unroll") \
      for (int cht_=0; cht_<8; cht_++){ \
        bf16x8 vf_ = *(const bf16x8*)(base_ + cht_*512 + lane*8); \
        accA[cht_] = __builtin_amdgcn_mfma_f32_32x32x16_bf16(pfA[ks_], vf_, accA[cht_], 0,0,0); \
        accB[cht_] = __builtin_amdgcn_mfma_f32_32x32x16_bf16(pfB[ks_], vf_, accB[cht_], 0,0,0); \
      } \
    } \
  } while(0)

  VPREF(0, sV0);

  f32x16 accA[8], accB[8];
  #pragma unroll
  for (int t=0;t<8;t++){ accA[t] = (f32x16)(0.f); accB[t] = (f32x16)(0.f); }
  float rsA = 0.f, rsB = 0.f;
  bf16x8 pfA[2], pfB[2];

  // prologue: S(0) from kE; refill kE <- K(2)
  QK2(kE0, kE1, pfA, pfB);
  kE0 = *(const bf16x8*)(kf0p + 2*2048);
  kE1 = *(const bf16x8*)(kf1p + 2*2048);
  __syncthreads();                              // stage(0) complete

  for (int j = 0; j < 32; j++){
    // ---- interval t=2j: PV(2j) from sV0; QK(2j+1) from kO; stage(2j+1)->sV1 ----
    {
      VPREF(2*j+1, sV1);
      bf16x8 nfA[2], nfB[2];
      QK2(kO0, kO1, nfA, nfB);
      if (j < 31){                              // refill kO <- K(2j+3)
        kO0 = *(const bf16x8*)(kf0p + (size_t)(2*j+3)*2048);
        kO1 = *(const bf16x8*)(kf1p + (size_t)(2*j+3)*2048);
      }
      PV2(sV0);
      pfA[0]=nfA[0]; pfA[1]=nfA[1]; pfB[0]=nfB[0]; pfB[1]=nfB[1];
      __syncthreads();
    }
    // ---- interval t=2j+1: PV(2j+1) from sV1; QK(2j+2) from kE; stage(2j+2)->sV0 ----
    {
      if (j < 31){
        VPREF(2*j+2, sV0);
        bf16x8 nfA[2], nfB[2];
        QK2(kE0, kE1, nfA, nfB);
        if (j < 30){                            // refill kE <- K(2j+4)
          kE0 = *(const bf16x8*)(kf0p + (size_t)(2*j+4)*2048);
          kE1 = *(const bf16x8*)(kf1p + (size_t)(2*j+4)*2048);
        }
        PV2(sV1);
        pfA[0]=nfA[0]; pfA[1]=nfA[1]; pfB[0]=nfB[0]; pfB[1]=nfB[1];
      } else {
        PV2(sV1);                               // final chunk 63
      }
      __syncthreads();
    }
  }

  // ---- epilogue ----
  // full rowsum for this wave's kv-half: merge h-interleaved kv rows
  rsA += __shfl_xor(rsA, 32);
  rsB += __shfl_xor(rsB, 32);

  float* R   = (float*)smem;                   // [wave][c(4)][i(16)][lane] = 64 KB
  float* RS  = (float*)(smem + 65536);         // [wave][2][32]            = 1 KB
  float* RSM = (float*)(smem + 66560);         // [wave][32] merged keep-rowsum
  int pw = wave ^ 1;
  if (lane < 32){ RS[wave*64 + l31] = rsA; RS[wave*64 + 32 + l31] = rsB; }

  // cross-kh merge. keep tile: kh0 -> A, kh1 -> B; give the other.
  // phase 1: cht 0..3 of give tile
  if (kh == 0){
    #pragma unroll
    for (int c=0;c<4;c++)
      #pragma unroll
      for (int i=0;i<16;i++) R[wave*4096 + c*1024 + i*64 + lane] = accB[c][i];
  } else {
    #pragma unroll
    for (int c=0;c<4;c++)
      #pragma unroll
      for (int i=0;i<16;i++) R[wave*4096 + c*1024 + i*64 + lane] = accA[c][i];
  }
  __syncthreads();
  {
    float rsT;
    if (kh == 0){
      #pragma unroll
      for (int c=0;c<4;c++)
        #pragma unroll
        for (int i=0;i<16;i++) accA[c][i] += R[pw*4096 + c*1024 + i*64 + lane];
      rsT = rsA + RS[pw*64 + l31];
    } else {
      #pragma unroll
      for (int c=0;c<4;c++)
        #pragma unroll
        for (int i=0;i<16;i++) accB[c][i] += R[pw*4096 + c*1024 + i*64 + lane];
      rsT = rsB + RS[pw*64 + 32 + l31];
    }
    if (lane < 32) RSM[wave*32 + l31] = rsT;
  }
  __syncthreads();
  // phase 2: cht 4..7 of give tile
  if (kh == 0){
    #pragma unroll
    for (int c=0;c<4;c++)
      #pragma unroll
      for (int i=0;i<16;i++) R[wave*4096 + c*1024 + i*64 + lane] = accB[4+c][i];
  } else {
    #pragma unroll
    for (int c=0;c<4;c++)
      #pragma unroll
      for (int i=0;i<16;i++) R[wave*4096 + c*1024 + i*64 + lane] = accA[4+c][i];
  }
  __syncthreads();
  if (kh == 0){
    #pragma unroll
    for (int c=0;c<4;c++)
      #pragma unroll
      for (int i=0;i<16;i++) accA[4+c][i] += R[pw*4096 + c*1024 + i*64 + lane];
  } else {
    #pragma unroll
    for (int c=0;c<4;c++)
      #pragma unroll
      for (int i=0;i<16;i++) accB[4+c][i] += R[pw*4096 + c*1024 + i*64 + lane];
  }

  // out = gamma*O/l + x ; wave writes its keep tile kt = qtp*2+kh: 32 q x 256 ch
  float g = *gptr;
  int kt = qtp*2 + kh;
  const float* xb = x + ((size_t)b*N_ + q0 + kt*32)*C_;
  float*       ob = out + ((size_t)b*N_ + q0 + kt*32)*C_;
  if (kh == 0){
    #pragma unroll
    for (int i=0;i<16;i++){
      int q = (i&3) + 8*(i>>2) + 4*h;
      float rv = 1.f / RSM[wave*32 + q];
      #pragma unroll
      for (int c=0;c<8;c++){
        int ch = c*32 + l31;
        ob[(size_t)q*C_ + ch] = g*(accA[c][i]*rv) + xb[(size_t)q*C_ + ch];
      }
    }
  } else {
    #pragma unroll
    for (int i=0;i<16;i++){
      int q = (i&3) + 8*(i>>2) + 4*h;
      float rv = 1.f / RSM[wave*32 + q];
      #pragma unroll
      for (int c=0;c<8;c++){
        int ch = c*32 + l31;
        ob[(size_t)q*C_ + ch] = g*(accB[c][i]*rv) + xb[(size_t)q*C_ + ch];
      }
    }
  }
#undef VPREF
#undef EXPPACK
#undef QK2
#undef PV2
}

extern "C" void kernel_launch(void* const* d_in, const int* in_sizes, int n_in,
                              void* d_out, int out_size, void* d_ws, size_t ws_size,
                              hipStream_t stream){
  const float* x  = (const float*)d_in[0];
  const float* Wq = (const float*)d_in[1];
  const float* bq = (const float*)d_in[2];
  const float* Wk = (const float*)d_in[3];
  const float* bk = (const float*)d_in[4];
  const float* Wv = (const float*)d_in[5];
  const float* bv = (const float*)d_in[6];
  const float* gm = (const float*)d_in[7];
  float* out = (float*)d_out;
  char* ws = (char*)d_ws;
  short* WT  = (short*)ws;                               // 163840 B
  short* qws = (short*)(ws + 163840);                    // 2097152 B
  short* kws = (short*)(ws + 163840 + 2097152);          // 2097152 B
  short* vSw = (short*)(ws + 163840 + 2*2097152);        // 16777216 B

  cast_wt_kernel<<<dim3(320), dim3(256), 0, stream>>>(Wq, Wk, Wv, WT);
  proj_kernel<<<dim3(512), dim3(256), 0, stream>>>(x, WT, bq, bk, bv, qws, kws, vSw);
  flash_kernel<<<dim3(256), dim3(256), 0, stream>>>(x, qws, kws, vSw, gm, out);
}

// Round 4
// 197.948 us; speedup vs baseline: 1.3283x; 1.3283x over previous
//
#include <hip/hip_runtime.h>
#include <hip/hip_bf16.h>
#include <math.h>

#define B_ 8
#define N_ 4096
#define C_ 256
#define DQK_ 32

typedef float f32x4  __attribute__((ext_vector_type(4)));
typedef float f32x16 __attribute__((ext_vector_type(16)));
typedef short bf16x8 __attribute__((ext_vector_type(8)));
typedef short bf16x4 __attribute__((ext_vector_type(4)));

__device__ __forceinline__ short f2bf(float f){
  union { float f; unsigned u; } v; v.f = f;
  unsigned r = v.u + 0x7fffu + ((v.u >> 16) & 1u);
  return (short)(r >> 16);
}

// ---------- kernel 1: weight transpose + cast -> WT[320][256] bf16 ----------
__global__ void cast_wt_kernel(const float* __restrict__ Wq, const float* __restrict__ Wk,
                               const float* __restrict__ Wv, short* __restrict__ WT){
  int n = blockIdx.x;        // 0..319 output channel
  int k = threadIdx.x;       // 0..255 input channel
  float val;
  if (n < 32)       val = Wq[k*32 + n];
  else if (n < 64)  val = Wk[k*32 + (n-32)];
  else              val = Wv[k*256 + (n-64)];
  WT[n*256 + k] = f2bf(val);
}

// ---------- kernel 2: projections -> frag-swizzled q,k,v ----------
__global__ __launch_bounds__(256) void proj_kernel(
    const float* __restrict__ x, const short* __restrict__ WT,
    const float* __restrict__ bq, const float* __restrict__ bk, const float* __restrict__ bv,
    short* __restrict__ qws, short* __restrict__ kws, short* __restrict__ vSw){
  __shared__ __align__(16) short sX[64*264];   // 67584 B
  __shared__ __align__(16) short sT[64*72];    // 9216 B  (q cols 0..31 | k cols 32..63)
  int tid = threadIdx.x;
  int lane = tid & 63, wave = tid >> 6;
  int lane15 = lane & 15, quad = lane >> 4;
  int mbase = blockIdx.x * 64;
  int b = mbase >> 12, kvb = mbase & (N_-1);

  const float* xr = x + (size_t)mbase * C_;
  for (int i = 0; i < 8; i++){
    int s = tid + i*256;
    int row = s >> 5, cg = (s & 31) << 3;
    const f32x4* src = (const f32x4*)(xr + row*C_ + cg);
    f32x4 a = src[0], c = src[1];
    bf16x8 p;
    p[0]=f2bf(a[0]); p[1]=f2bf(a[1]); p[2]=f2bf(a[2]); p[3]=f2bf(a[3]);
    p[4]=f2bf(c[0]); p[5]=f2bf(c[1]); p[6]=f2bf(c[2]); p[7]=f2bf(c[3]);
    *(bf16x8*)(sX + row*264 + cg) = p;
  }
  __syncthreads();

  f32x4 acc[5][4];
  for (int i=0;i<5;i++) for (int mt=0;mt<4;mt++) acc[i][mt] = (f32x4)(0.f);

  for (int kc = 0; kc < 8; kc++){
    bf16x8 afr[4];
    #pragma unroll
    for (int mt=0;mt<4;mt++)
      afr[mt] = *(const bf16x8*)(sX + (mt*16+lane15)*264 + kc*32 + quad*8);
    bf16x8 bfr[5];
    #pragma unroll
    for (int i=0;i<5;i++){
      int t = i*4 + wave;
      bfr[i] = *(const bf16x8*)(WT + (size_t)(t*16+lane15)*256 + kc*32 + quad*8);
    }
    #pragma unroll
    for (int i=0;i<5;i++)
      #pragma unroll
      for (int mt=0;mt<4;mt++)
        acc[i][mt] = __builtin_amdgcn_mfma_f32_16x16x32_bf16(afr[mt], bfr[i], acc[i][mt], 0,0,0);
  }

  #pragma unroll
  for (int i=0;i<5;i++){
    int t = i*4 + wave;
    int n0 = t*16 + lane15;
    float bias = (n0 < 32) ? bq[n0] : (n0 < 64 ? bk[n0-32] : bv[n0-64]);
    if (n0 < 64){
      #pragma unroll
      for (int mt=0;mt<4;mt++)
        #pragma unroll
        for (int r=0;r<4;r++)
          sT[(mt*16 + quad*4 + r)*72 + n0] = f2bf(acc[i][mt][r] + bias);
    } else {
      int ch = n0 - 64, cht = ch >> 5, c5 = ch & 31;
      int lanep = c5 | ((quad & 1) << 5);
      int jo = (quad >> 1) * 4;
      #pragma unroll
      for (int mt=0;mt<4;mt++){
        bf16x4 pk;
        pk[0]=f2bf(acc[i][mt][0]+bias); pk[1]=f2bf(acc[i][mt][1]+bias);
        pk[2]=f2bf(acc[i][mt][2]+bias); pk[3]=f2bf(acc[i][mt][3]+bias);
        size_t off = (size_t)b*1048576 + (size_t)(kvb>>6)*16384
                   + (size_t)(mt*8 + cht)*512 + (size_t)lanep*8 + jo;
        *(bf16x4*)(vSw + off) = pk;
      }
    }
  }
  __syncthreads();

  {
    int qt = tid >> 7, p = (tid >> 6) & 1, ln = tid & 63;
    int row = qt*32 + (ln & 31);
    int dcol = p*16 + (ln >> 5)*8;
    bf16x8 vq = *(const bf16x8*)(sT + row*72 + dcol);
    bf16x8 vk = *(const bf16x8*)(sT + row*72 + 32 + dcol);
    size_t qoff = ((((size_t)b*128 + ((kvb>>5) + qt))*2 + p)*64 + ln)*8;
    *(bf16x8*)(qws + qoff) = vq;
    size_t koff = ((size_t)b*64 + (kvb>>6))*2048 + (size_t)((qt*2 + p)*64 + ln)*8;
    *(bf16x8*)(kws + koff) = vk;
  }
}

// ---------- kernel 3: flash attention + residual (v5: channel-split V reuse) ----------
// grid 256 (1 block/CU), block 512 thr = 8 waves (2/SIMD).
// wave = qp*4 + cd*2 + kh: q-pair qp (tiles 2qp,2qp+1), channel-half cd (128 ch),
// kv-half kh (32 kv rows of each 64-chunk).
// vs v1 (90.8us): each V fragment read feeds 2 MFMAs (both q-tiles) -> V LDS reads
// 128->64 KB/chunk/CU; total LDS 160->96 KB (v3 showed LDS traffic is critical-path
// at ~85 B/cyc). QK is duplicated across cd waves (+16 MFMA/chunk/CU) but the
// ones-MFMA rowsum is replaced by VALU adds (-16 MFMA, numerics validated in v4) ->
// MFMA count unchanged at 160/chunk/CU.
// Register budget (must stay <=256 for 2 waves/SIMD): acc 8xf32x16=128 + Q 32 +
// pf 32 + kfc 16 + S-transient 16 (A/B interleaved, never both live) + misc ~20 = ~244.
// No kfn prefetch pair: kfc is dead after QK, next chunk's K loads IN-PLACE right
// after; the end-of-chunk barrier's vmcnt(0) drain covers the latency (0 extra regs).
__global__ __launch_bounds__(512, 2) void flash_kernel(
    const float* __restrict__ x, const short* __restrict__ qws, const short* __restrict__ kws,
    const short* __restrict__ vSw, const float* __restrict__ gptr, float* __restrict__ out){
  __shared__ __align__(16) char smem[67584];   // main: sV[2][32KB]; epi: R 64KB + RS 2KB
  short* sV0 = (short*)smem;
  short* sV1 = (short*)(smem + 32768);
  int tid = threadIdx.x;
  int lane = tid & 63, wave = tid >> 6;        // wave 0..7
  int l31 = lane & 31, h = lane >> 5;
  int qp = wave >> 2, cd = (wave >> 1) & 1, kh = wave & 1;
  int b = blockIdx.x & 7;
  int q0 = (blockIdx.x >> 3) << 7;             // 128 q-rows per block

  const short* qb = qws + (size_t)b*131072;
  const short* kb = kws + (size_t)b*131072;
  const short* vb = vSw + (size_t)b*1048576;

  int qtgA = (q0 >> 5) + qp*2;                 // global q-tile ids: qtgA, qtgA+1
  bf16x8 qfA0 = *(const bf16x8*)(qb + (size_t)((qtgA*2+0)*64 + lane)*8);
  bf16x8 qfA1 = *(const bf16x8*)(qb + (size_t)((qtgA*2+1)*64 + lane)*8);
  bf16x8 qfB0 = *(const bf16x8*)(qb + (size_t)(((qtgA+1)*2+0)*64 + lane)*8);
  bf16x8 qfB1 = *(const bf16x8*)(qb + (size_t)(((qtgA+1)*2+1)*64 + lane)*8);

  const short* kf0p = kb + (size_t)((2*kh+0)*64 + lane)*8;
  const short* kf1p = kb + (size_t)((2*kh+1)*64 + lane)*8;
  bf16x8 kfc0 = *(const bf16x8*)(kf0p);        // K(0), reloaded in-place each chunk
  bf16x8 kfc1 = *(const bf16x8*)(kf1p);

#define VPREF(CHUNK, DST) do { \
    const short* vsrc_ = vb + (size_t)(CHUNK)*16384; \
    _Pragma("unroll") \
    for (int r_=0;r_<4;r_++) \
      __builtin_amdgcn_global_load_lds( \
        (const __attribute__((address_space(1))) void*)(vsrc_ + (size_t)(r_*512+tid)*8), \
        (__attribute__((address_space(3))) void*)((DST) + (size_t)(r_*512+tid)*8), 16, 0, 0); \
  } while(0)

#define EXPPACK(S, PF, RS) do { \
    float ls_ = 0.f; \
    _Pragma("unroll") \
    for (int g_=0; g_<2; g_++){ \
      union { bf16x8 v; unsigned u[4]; } P_; \
      _Pragma("unroll") \
      for (int j_=0;j_<4;j_++){ \
        float2 e_; \
        e_.x = __expf((S)[g_*8 + 2*j_]); \
        e_.y = __expf((S)[g_*8 + 2*j_ + 1]); \
        ls_ += e_.x + e_.y; \
        __hip_bfloat162 t2_ = __float22bfloat162_rn(e_); \
        __builtin_memcpy(&P_.u[j_], &t2_, 4); \
      } \
      (PF)[g_] = P_.v; \
    } \
    (RS) += ls_; \
  } while(0)

  VPREF(0, sV0);
  __syncthreads();

  f32x16 accA[4], accB[4];
  #pragma unroll
  for (int t=0;t<4;t++){ accA[t] = (f32x16)(0.f); accB[t] = (f32x16)(0.f); }
  float rsA = 0.f, rsB = 0.f;

  for (int it=0; it<64; it++){
    short* sVc = (it & 1) ? sV1 : sV0;
    short* sVn = (it & 1) ? sV0 : sV1;
    if (it < 63) VPREF(it+1, sVn);

    bf16x8 pfA[2], pfB[2];
    // tile A: S^T (32 kv x 32 q), then exp+pack (S-transient dies before tile B's S)
    {
      f32x16 s = __builtin_amdgcn_mfma_f32_32x32x16_bf16(kfc0, qfA0, (f32x16)(0.f), 0,0,0);
      s        = __builtin_amdgcn_mfma_f32_32x32x16_bf16(kfc1, qfA1, s, 0,0,0);
      EXPPACK(s, pfA, rsA);
    }
    // tile B
    {
      f32x16 s = __builtin_amdgcn_mfma_f32_32x32x16_bf16(kfc0, qfB0, (f32x16)(0.f), 0,0,0);
      s        = __builtin_amdgcn_mfma_f32_32x32x16_bf16(kfc1, qfB1, s, 0,0,0);
      EXPPACK(s, pfB, rsB);
    }
    // kfc dead -> reload in place for next chunk (latency covered by end barrier)
    if (it < 63){
      kfc0 = *(const bf16x8*)(kf0p + (size_t)(it+1)*2048);
      kfc1 = *(const bf16x8*)(kf1p + (size_t)(it+1)*2048);
    }

    // PV: each V frag (this wave's 4 cht of its cd half) feeds BOTH tiles
    #pragma unroll
    for (int ks=0; ks<2; ks++){
      const short* base = sVc + (2*kh + ks)*4096;
      #pragma unroll
      for (int c=0; c<4; c++){
        bf16x8 vf = *(const bf16x8*)(base + ((cd*4+c)*64 + lane)*8);
        accA[c] = __builtin_amdgcn_mfma_f32_32x32x16_bf16(pfA[ks], vf, accA[c], 0,0,0);
        accB[c] = __builtin_amdgcn_mfma_f32_32x32x16_bf16(pfB[ks], vf, accB[c], 0,0,0);
      }
    }
    __syncthreads();
  }

  // ---- rowsum: merge h-interleaved kv rows; publish from cd==0 waves ----
  rsA += __shfl_xor(rsA, 32);
  rsB += __shfl_xor(rsB, 32);
  float* R  = (float*)smem;                    // [wave][j(2)][i(16)][lane] = 64 KB
  float* RS = (float*)(smem + 65536);          // [wave][2][32]             = 2 KB
  int pw = wave ^ 1;                           // partner: same (qp,cd), other kh
  if (cd == 0 && lane < 32){ RS[wave*64 + l31] = rsA; RS[wave*64 + 32 + l31] = rsB; }

  // ---- cross-kh merge: kh0 keeps tile A, kh1 keeps tile B; give the other ----
  // phase 1: accs 0,1 of give tile
  if (kh == 0){
    #pragma unroll
    for (int i=0;i<16;i++){ R[wave*2048 + i*64 + lane] = accB[0][i];
                            R[wave*2048 + 1024 + i*64 + lane] = accB[1][i]; }
  } else {
    #pragma unroll
    for (int i=0;i<16;i++){ R[wave*2048 + i*64 + lane] = accA[0][i];
                            R[wave*2048 + 1024 + i*64 + lane] = accA[1][i]; }
  }
  __syncthreads();
  if (kh == 0){
    #pragma unroll
    for (int i=0;i<16;i++){ accA[0][i] += R[pw*2048 + i*64 + lane];
                            accA[1][i] += R[pw*2048 + 1024 + i*64 + lane]; }
  } else {
    #pragma unroll
    for (int i=0;i<16;i++){ accB[0][i] += R[pw*2048 + i*64 + lane];
                            accB[1][i] += R[pw*2048 + 1024 + i*64 + lane]; }
  }
  __syncthreads();
  // phase 2: accs 2,3 of give tile
  if (kh == 0){
    #pragma unroll
    for (int i=0;i<16;i++){ R[wave*2048 + i*64 + lane] = accB[2][i];
                            R[wave*2048 + 1024 + i*64 + lane] = accB[3][i]; }
  } else {
    #pragma unroll
    for (int i=0;i<16;i++){ R[wave*2048 + i*64 + lane] = accA[2][i];
                            R[wave*2048 + 1024 + i*64 + lane] = accA[3][i]; }
  }
  __syncthreads();
  if (kh == 0){
    #pragma unroll
    for (int i=0;i<16;i++){ accA[2][i] += R[pw*2048 + i*64 + lane];
                            accA[3][i] += R[pw*2048 + 1024 + i*64 + lane]; }
  } else {
    #pragma unroll
    for (int i=0;i<16;i++){ accB[2][i] += R[pw*2048 + i*64 + lane];
                            accB[3][i] += R[pw*2048 + 1024 + i*64 + lane]; }
  }

  // ---- epilogue: out = gamma*O/l + x ----
  // wave writes tile kt = qp*2+kh (32 q rows), channels [cd*128, +128)
  float g = *gptr;
  int kt = qp*2 + kh;
  int w0 = qp*4, w1 = qp*4 + 1;                // cd=0 publishers for kh=0,1
  int sel = kh*32;                             // kept tile: A->rsA(0), B->rsB(32)
  const float* xb = x + ((size_t)b*N_ + q0 + kt*32)*C_;
  float*       ob = out + ((size_t)b*N_ + q0 + kt*32)*C_;
  if (kh == 0){
    #pragma unroll
    for (int i=0;i<16;i++){
      int q = (i&3) + 8*(i>>2) + 4*h;
      float rv = 1.f / (RS[w0*64 + sel + q] + RS[w1*64 + sel + q]);
      #pragma unroll
      for (int c=0;c<4;c++){
        int ch = (cd*4 + c)*32 + l31;
        ob[(size_t)q*C_ + ch] = g*(accA[c][i]*rv) + xb[(size_t)q*C_ + ch];
      }
    }
  } else {
    #pragma unroll
    for (int i=0;i<16;i++){
      int q = (i&3) + 8*(i>>2) + 4*h;
      float rv = 1.f / (RS[w0*64 + sel + q] + RS[w1*64 + sel + q]);
      #pragma unroll
      for (int c=0;c<4;c++){
        int ch = (cd*4 + c)*32 + l31;
        ob[(size_t)q*C_ + ch] = g*(accB[c][i]*rv) + xb[(size_t)q*C_ + ch];
      }
    }
  }
#undef VPREF
#undef EXPPACK
}

extern "C" void kernel_launch(void* const* d_in, const int* in_sizes, int n_in,
                              void* d_out, int out_size, void* d_ws, size_t ws_size,
                              hipStream_t stream){
  const float* x  = (const float*)d_in[0];
  const float* Wq = (const float*)d_in[1];
  const float* bq = (const float*)d_in[2];
  const float* Wk = (const float*)d_in[3];
  const float* bk = (const float*)d_in[4];
  const float* Wv = (const float*)d_in[5];
  const float* bv = (const float*)d_in[6];
  const float* gm = (const float*)d_in[7];
  float* out = (float*)d_out;
  char* ws = (char*)d_ws;
  short* WT  = (short*)ws;                               // 163840 B
  short* qws = (short*)(ws + 163840);                    // 2097152 B
  short* kws = (short*)(ws + 163840 + 2097152);          // 2097152 B
  short* vSw = (short*)(ws + 163840 + 2*2097152);        // 16777216 B

  cast_wt_kernel<<<dim3(320), dim3(256), 0, stream>>>(Wq, Wk, Wv, WT);
  proj_kernel<<<dim3(512), dim3(256), 0, stream>>>(x, WT, bq, bk, bv, qws, kws, vSw);
  flash_kernel<<<dim3(256), dim3(512), 0, stream>>>(x, qws, kws, vSw, gm, out);
}